// Round 7
// baseline (404.571 us; speedup 1.0000x reference)
//
#include <hip/hip_runtime.h>
#include <stdint.h>

typedef _Float16 f16;
typedef __attribute__((ext_vector_type(8))) _Float16 f16x8;
typedef __attribute__((ext_vector_type(4))) float f32x4;

#define NN 4096
#define UN 256

__device__ __forceinline__ f16x8 ld_f16x8(const f16* p){ return *(const f16x8*)p; }
__device__ __forceinline__ f32x4 zero4(){ f32x4 z = {0.f,0.f,0.f,0.f}; return z; }

// Fragment-major B layout: [k/32][n/16][lane=((k>>3)&3)*16+(n&15)][j=k&7] f16.
// A wave loads fragment (kc,nt) as one coalesced 1KB read: base + lane*8.

// ---------------- K0: build wgB (f16 frag-major) + gate frag buffers ------
__global__ __launch_bounds__(256) void k0_prep(
    const float* __restrict__ wg, const float* __restrict__ wz,
    const float* __restrict__ uz, const float* __restrict__ wh,
    const float* __restrict__ uh,
    f16* __restrict__ wgB,
    f16* __restrict__ czB_h, f16* __restrict__ czB_l,
    f16* __restrict__ chB_h, f16* __restrict__ chB_l)
{
  __shared__ float lsA[32*256];
  __shared__ float lsB[32*256];
  const int t = threadIdx.x;
  const int b = blockIdx.x;
  if (b < 128){
    const int kcg = b;
    #pragma unroll 8
    for (int i = 0; i < 32; i++)
      lsA[i*256 + t] = wg[(size_t)(kcg*32 + i) * UN + t];
    __syncthreads();
    #pragma unroll
    for (int i = 0; i < 4; i++){
      int o = i*256 + t;
      int l = o & 63;
      int n = ((o >> 6) << 4) + (l & 15);
      int kl = (l >> 4) * 8;
      f16 v8[8];
      #pragma unroll
      for (int j = 0; j < 8; j++) v8[j] = (f16)lsA[(kl + j)*256 + n];
      *(uint4*)(wgB + ((size_t)kcg*1024 + o)*8) = *(const uint4*)v8;
    }
  } else {
    const int kcg = b - 128;           // 0..15, K=512
    #pragma unroll 8
    for (int i = 0; i < 32; i++){
      int kg = kcg*32 + i;
      lsA[i*256 + t] = (kg < 256) ? wz[(size_t)kg * UN + t]
                                  : uz[(size_t)(kg - 256) * UN + t];
      lsB[i*256 + t] = (kg < 256) ? wh[(size_t)kg * UN + t]
                                  : uh[(size_t)(kg - 256) * UN + t];
    }
    __syncthreads();
    #pragma unroll
    for (int i = 0; i < 4; i++){
      int o = i*256 + t;
      int l = o & 63;
      int n = ((o >> 6) << 4) + (l & 15);
      int kl = (l >> 4) * 8;
      f16 zh[8], zl[8], hh[8], hl[8];
      #pragma unroll
      for (int j = 0; j < 8; j++){
        float vz = lsA[(kl + j)*256 + n];
        float vh = lsB[(kl + j)*256 + n];
        f16 a = (f16)vz; zh[j] = a; zl[j] = (f16)(vz - (float)a);
        f16 c = (f16)vh; hh[j] = c; hl[j] = (f16)(vh - (float)c);
      }
      size_t off = ((size_t)kcg*1024 + o)*8;
      *(uint4*)(czB_h + off) = *(const uint4*)zh;
      *(uint4*)(czB_l + off) = *(const uint4*)zl;
      *(uint4*)(chB_h + off) = *(const uint4*)hh;
      *(uint4*)(chB_l + off) = *(const uint4*)hl;
    }
  }
}

__device__ __forceinline__ void k1_loadA(f32x4 (&g)[6], const float* p, size_t gs){
  #pragma unroll
  for (int gi = 0; gi < 3; gi++){
    g[gi*2]   = *(const f32x4*)(p + (size_t)gi*gs);
    g[gi*2+1] = *(const f32x4*)(p + (size_t)gi*gs + 4);
  }
}

// ---------------- K1: W2[node][unit] += (sum_g wa_g adj_g) @ w_gcn --------
// No LDS/barriers. Wave = 16m x 128n (8 acc frags). Block = 32m x 256n.
// Grid (128 m-tiles, 16 k-splits of 256). Distance-2 A prefetch via parity
// register buffers; 4 waves/SIMD forced to hide HBM latency with TLP.
__global__ __launch_bounds__(256, 4) void k1_w2(
    const float* __restrict__ adj, const float* __restrict__ wa,
    const f16* __restrict__ wgB, float* __restrict__ W2)
{
  const int t = threadIdx.x, lane = t & 63, wv = t >> 6;
  const int qm = lane & 15, quad = lane >> 4;
  const int mh = wv & 1, nh = wv >> 1;      // m-half (16 rows), n-half (8 frags)
  const int mbase = blockIdx.x * 32;
  const int kbase = blockIdx.y * 256;
  const float wa0 = wa[0], wa1 = wa[1], wa2 = wa[2];
  const size_t gs = (size_t)NN * NN;
  const float* pa = adj + (size_t)(mbase + mh*16 + qm) * NN + kbase + quad * 8;

  f32x4 acc[8];
  #pragma unroll
  for (int i = 0; i < 8; i++) acc[i] = zero4();

  f32x4 g[2][6];
  k1_loadA(g[0], pa, gs);
  k1_loadA(g[1], pa + 32, gs);

  #pragma unroll
  for (int s = 0; s < 8; s++){
    f32x4 (&gc)[6] = g[s & 1];
    // mix current A (consumes gc)
    f16x8 ah, al;
    #pragma unroll
    for (int j = 0; j < 4; j++){
      float v0 = wa0*gc[0][j] + wa1*gc[2][j] + wa2*gc[4][j];
      float v1 = wa0*gc[1][j] + wa1*gc[3][j] + wa2*gc[5][j];
      f16 h0 = (f16)v0, h1 = (f16)v1;
      ah[j] = h0;   al[j] = (f16)(v0 - (float)h0);
      ah[4+j] = h1; al[4+j] = (f16)(v1 - (float)h1);
    }
    // distance-2 prefetch into the registers just consumed
    if (s < 6) k1_loadA(gc, pa + (s+2)*32, gs);

    const int kcg = (kbase + s*32) >> 5;
    const f16* pb = wgB + ((size_t)kcg*1024 + nh*512 + lane)*8;
    f16x8 b0[4];
    #pragma unroll
    for (int i = 0; i < 4; i++) b0[i] = ld_f16x8(pb + i*512);
    #pragma unroll
    for (int tn = 0; tn < 4; tn++){
      acc[tn] = __builtin_amdgcn_mfma_f32_16x16x32_f16(ah, b0[tn], acc[tn], 0, 0, 0);
      acc[tn] = __builtin_amdgcn_mfma_f32_16x16x32_f16(al, b0[tn], acc[tn], 0, 0, 0);
    }
    f16x8 b1[4];
    #pragma unroll
    for (int i = 0; i < 4; i++) b1[i] = ld_f16x8(pb + (4+i)*512);
    #pragma unroll
    for (int tn = 0; tn < 4; tn++){
      acc[4+tn] = __builtin_amdgcn_mfma_f32_16x16x32_f16(ah, b1[tn], acc[4+tn], 0, 0, 0);
      acc[4+tn] = __builtin_amdgcn_mfma_f32_16x16x32_f16(al, b1[tn], acc[4+tn], 0, 0, 0);
    }
  }

  // epilogue: D[m=quad*4+r][n=(nh*8+tn)*16+qm]; 64B-coalesced f32 atomics
  #pragma unroll
  for (int tn = 0; tn < 8; tn++)
    #pragma unroll
    for (int r = 0; r < 4; r++)
      atomicAdd(&W2[(size_t)(mbase + mh*16 + quad*4 + r)*UN + (nh*8 + tn)*16 + qm],
                acc[tn][r]);
}

// ---------------- Kcvt: W2 f32 [4096][256] -> W2B f16 frag-major ----------
__global__ __launch_bounds__(256) void k_cvt(
    const float* __restrict__ W2, f16* __restrict__ W2B)
{
  __shared__ float ls[32*256];
  const int t = threadIdx.x;
  const int kcg = blockIdx.x;            // 0..127
  #pragma unroll 8
  for (int i = 0; i < 32; i++)
    ls[i*256 + t] = W2[(size_t)(kcg*32 + i) * UN + t];
  __syncthreads();
  #pragma unroll
  for (int i = 0; i < 4; i++){
    int o = i*256 + t;
    int l = o & 63;
    int n = ((o >> 6) << 4) + (l & 15);
    int kl = (l >> 4) * 8;
    f16 v8[8];
    #pragma unroll
    for (int j = 0; j < 8; j++) v8[j] = (f16)ls[(kl + j)*256 + n];
    *(uint4*)(W2B + ((size_t)kcg*1024 + o)*8) = *(const uint4*)v8;
  }
}

// ---------------- K2: xg[m][n] += inputs @ W2 -----------------------------
// Grid (32 m-tiles of 16, 32 k-splits of 128). Parity-buffer prefetch.
__global__ __launch_bounds__(256) void k2_x(
    const float* __restrict__ inputs, const f16* __restrict__ W2B,
    float* __restrict__ xg)
{
  const int t = threadIdx.x, lane = t & 63, wv = t >> 6;
  const int qm = lane & 15, quad = lane >> 4;
  const int m0 = blockIdx.x * 16;
  const int kbase = blockIdx.y * 128;
  const float* pa = inputs + (size_t)(m0 + qm) * NN + kbase + quad * 8;

  f32x4 acc[4] = { zero4(), zero4(), zero4(), zero4() };

  f32x4 a0 = *(const f32x4*)pa;
  f32x4 a1 = *(const f32x4*)(pa + 4);
  f16x8 bf[4];
  {
    const f16* pb = W2B + (((size_t)(kbase >> 5)*16 + wv*4)*64 + lane)*8;
    #pragma unroll
    for (int i = 0; i < 4; i++) bf[i] = ld_f16x8(pb + i*512);
  }

  #pragma unroll
  for (int kc = 0; kc < 128; kc += 32){
    f32x4 na0, na1; f16x8 nb[4];
    if (kc < 96){
      na0 = *(const f32x4*)(pa + kc + 32);
      na1 = *(const f32x4*)(pa + kc + 36);
      const f16* pbn = W2B + (((size_t)((kbase + kc + 32) >> 5)*16 + wv*4)*64 + lane)*8;
      #pragma unroll
      for (int i = 0; i < 4; i++) nb[i] = ld_f16x8(pbn + i*512);
    }
    f16x8 ah, al;
    #pragma unroll
    for (int j = 0; j < 4; j++){
      f16 h0 = (f16)a0[j], h1 = (f16)a1[j];
      ah[j] = h0;   al[j] = (f16)(a0[j] - (float)h0);
      ah[4+j] = h1; al[4+j] = (f16)(a1[j] - (float)h1);
    }
    #pragma unroll
    for (int tn = 0; tn < 4; tn++){
      acc[tn] = __builtin_amdgcn_mfma_f32_16x16x32_f16(ah, bf[tn], acc[tn], 0, 0, 0);
      acc[tn] = __builtin_amdgcn_mfma_f32_16x16x32_f16(al, bf[tn], acc[tn], 0, 0, 0);
    }
    a0 = na0; a1 = na1;
    #pragma unroll
    for (int i = 0; i < 4; i++) bf[i] = nb[i];
  }
  #pragma unroll
  for (int tn = 0; tn < 4; tn++)
    #pragma unroll
    for (int r = 0; r < 4; r++)
      atomicAdd(&xg[(size_t)(m0 + quad*4 + r)*UN + (wv*4 + tn)*16 + qm],
                acc[tn][r]);
}

// ---------------- K3: gate logits via MFMA; relu+split fused --------------
// Grid (32 m-tiles of 16, 16 k-splits of 32). A read directly from xg/state.
__global__ __launch_bounds__(256) void k3_gates(
    const float* __restrict__ xg, const float* __restrict__ state,
    const f16* __restrict__ czB_h, const f16* __restrict__ czB_l,
    const f16* __restrict__ chB_h, const f16* __restrict__ chB_l,
    float* __restrict__ lz, float* __restrict__ lh)
{
  const int t = threadIdx.x, lane = t & 63, wv = t >> 6;
  const int qm = lane & 15, quad = lane >> 4;
  const int m0 = blockIdx.x * 16;
  const int kbase = blockIdx.y * 32;
  const bool rl = (kbase < 256);
  const float* asrc = rl ? (xg + (size_t)(m0 + qm)*UN + kbase + quad*8)
                         : (state + (size_t)(m0 + qm)*UN + (kbase - 256) + quad*8);

  f32x4 a0 = *(const f32x4*)asrc;
  f32x4 a1 = *(const f32x4*)(asrc + 4);
  f16x8 ah, al;
  #pragma unroll
  for (int j = 0; j < 4; j++){
    float v0 = rl ? fmaxf(a0[j], 0.f) : a0[j];
    float v1 = rl ? fmaxf(a1[j], 0.f) : a1[j];
    f16 h0 = (f16)v0, h1 = (f16)v1;
    ah[j] = h0;   al[j] = (f16)(v0 - (float)h0);
    ah[4+j] = h1; al[4+j] = (f16)(v1 - (float)h1);
  }

  f32x4 az[4] = { zero4(), zero4(), zero4(), zero4() };
  f32x4 ag[4] = { zero4(), zero4(), zero4(), zero4() };
  const int kcg = kbase >> 5;
  const size_t base = (((size_t)kcg*16 + wv*4)*64 + lane)*8;
  #pragma unroll
  for (int tn = 0; tn < 4; tn++){
    f16x8 bzh = ld_f16x8(czB_h + base + tn*512);
    f16x8 bzl = ld_f16x8(czB_l + base + tn*512);
    f16x8 bhh = ld_f16x8(chB_h + base + tn*512);
    f16x8 bhl = ld_f16x8(chB_l + base + tn*512);
    az[tn] = __builtin_amdgcn_mfma_f32_16x16x32_f16(ah, bzh, az[tn], 0, 0, 0);
    az[tn] = __builtin_amdgcn_mfma_f32_16x16x32_f16(al, bzh, az[tn], 0, 0, 0);
    az[tn] = __builtin_amdgcn_mfma_f32_16x16x32_f16(ah, bzl, az[tn], 0, 0, 0);
    ag[tn] = __builtin_amdgcn_mfma_f32_16x16x32_f16(ah, bhh, ag[tn], 0, 0, 0);
    ag[tn] = __builtin_amdgcn_mfma_f32_16x16x32_f16(al, bhh, ag[tn], 0, 0, 0);
    ag[tn] = __builtin_amdgcn_mfma_f32_16x16x32_f16(ah, bhl, ag[tn], 0, 0, 0);
  }
  #pragma unroll
  for (int tn = 0; tn < 4; tn++)
    #pragma unroll
    for (int r = 0; r < 4; r++){
      size_t o = (size_t)(m0 + quad*4 + r)*UN + (wv*4 + tn)*16 + qm;
      atomicAdd(&lz[o], az[tn][r]);
      atomicAdd(&lh[o], ag[tn][r]);
    }
}

// ---------------- K3b: elementwise gates + output -------------------------
__global__ __launch_bounds__(256) void k3b_out(
    const float* __restrict__ lz, const float* __restrict__ lh,
    const float* __restrict__ state,
    const float* __restrict__ bz, const float* __restrict__ bh,
    float* __restrict__ out)
{
  const size_t e = ((size_t)blockIdx.x * 256 + threadIdx.x) * 4;
  const int n = (int)(e & 255);
  f32x4 z4 = *(const f32x4*)(lz + e);
  f32x4 h4 = *(const f32x4*)(lh + e);
  f32x4 s4 = *(const f32x4*)(state + e);
  f32x4 bz4 = *(const f32x4*)(bz + n);
  f32x4 bh4 = *(const f32x4*)(bh + n);
  f32x4 o4;
  #pragma unroll
  for (int j = 0; j < 4; j++){
    float z = 1.f / (1.f + __expf(-(z4[j] + bz4[j])));
    float ex = __expf(2.f * (h4[j] + bh4[j]));
    float hh = 1.f - 2.f / (ex + 1.f);
    o4[j] = (1.f - z) * s4[j] + z * hh;
  }
  *(f32x4*)(out + e) = o4;
}

// ---------------- launch --------------------------------------------------
extern "C" void kernel_launch(void* const* d_in, const int* in_sizes, int n_in,
                              void* d_out, int out_size, void* d_ws, size_t ws_size,
                              hipStream_t stream)
{
  const float* inputs = (const float*)d_in[0];
  const float* state  = (const float*)d_in[1];
  const float* adj    = (const float*)d_in[2];
  const float* wa     = (const float*)d_in[3];
  const float* wg     = (const float*)d_in[4];
  const float* wz     = (const float*)d_in[5];
  const float* uz     = (const float*)d_in[6];
  const float* bz     = (const float*)d_in[7];
  const float* wh     = (const float*)d_in[8];
  const float* uh     = (const float*)d_in[9];
  const float* bh     = (const float*)d_in[10];
  float* out = (float*)d_out;

  char* ws = (char*)d_ws;
  float* W2    = (float*)(ws);                          // 4 MB [4096][256] f32
  float* xg    = (float*)(ws + (4u<<20));               // 512 KB [512][256]
  float* lz    = (float*)(ws + (4u<<20) + (512u<<10));  // 512 KB
  float* lh    = (float*)(ws + (5u<<20));               // 512 KB
  f16* wgB     = (f16*)(ws + (5u<<20) + (512u<<10));    // 2 MB frag-major
  f16* W2B     = (f16*)(ws + (7u<<20) + (512u<<10));    // 2 MB frag-major
  f16* czB_h   = (f16*)(ws + (9u<<20) + (512u<<10));    // 256 KB
  f16* czB_l   = (f16*)(ws + (9u<<20) + (768u<<10));    // 256 KB
  f16* chB_h   = (f16*)(ws + (10u<<20));                // 256 KB
  f16* chB_l   = (f16*)(ws + (10u<<20) + (256u<<10));   // 256 KB

  // zero W2 + xg + lz + lh (contiguous 5.5 MB)
  hipMemsetAsync(ws, 0, (5u<<20) + (512u<<10), stream);
  k0_prep<<<144, 256, 0, stream>>>(wg, wz, uz, wh, uh,
                                   wgB, czB_h, czB_l, chB_h, chB_l);
  k1_w2<<<dim3(128, 16), 256, 0, stream>>>(adj, wa, wgB, W2);
  k_cvt<<<128, 256, 0, stream>>>(W2, W2B);
  k2_x<<<dim3(32, 32), 256, 0, stream>>>(inputs, W2B, xg);
  k3_gates<<<dim3(32, 16), 256, 0, stream>>>(xg, state, czB_h, czB_l,
                                             chB_h, chB_l, lz, lh);
  k3b_out<<<128, 256, 0, stream>>>(lz, lh, state, bz, bh, out);
}

// Round 8
// 383.234 us; speedup vs baseline: 1.0557x; 1.0557x over previous
//
#include <hip/hip_runtime.h>
#include <stdint.h>

typedef _Float16 f16;
typedef __attribute__((ext_vector_type(8))) _Float16 f16x8;
typedef __attribute__((ext_vector_type(4))) float f32x4;

#define NN 4096
#define UN 256

__device__ __forceinline__ f16x8 ld_f16x8(const f16* p){ return *(const f16x8*)p; }
__device__ __forceinline__ f32x4 zero4(){ f32x4 z = {0.f,0.f,0.f,0.f}; return z; }

// async global->LDS, 16B per lane; LDS dest = wave-uniform base + lane*16
__device__ __forceinline__ void stage16(float* l, const float* g){
  __builtin_amdgcn_global_load_lds((const __attribute__((address_space(1))) void*)g,
                                   (__attribute__((address_space(3))) void*)l,
                                   16, 0, 0);
}

// Fragment-major B layout: [k/32][n/16][lane=((k>>3)&3)*16+(n&15)][j=k&7] f16.
// A wave loads fragment (kc,nt) as one coalesced 1KB read: base + lane*8.

// ---------------- K0: build wgB (f16 frag-major) + gate frag buffers ------
__global__ __launch_bounds__(256) void k0_prep(
    const float* __restrict__ wg, const float* __restrict__ wz,
    const float* __restrict__ uz, const float* __restrict__ wh,
    const float* __restrict__ uh,
    f16* __restrict__ wgB,
    f16* __restrict__ czB_h, f16* __restrict__ czB_l,
    f16* __restrict__ chB_h, f16* __restrict__ chB_l)
{
  __shared__ float lsA[32*256];
  __shared__ float lsB[32*256];
  const int t = threadIdx.x;
  const int b = blockIdx.x;
  if (b < 128){
    const int kcg = b;
    #pragma unroll 8
    for (int i = 0; i < 32; i++)
      lsA[i*256 + t] = wg[(size_t)(kcg*32 + i) * UN + t];
    __syncthreads();
    #pragma unroll
    for (int i = 0; i < 4; i++){
      int o = i*256 + t;
      int l = o & 63;
      int n = ((o >> 6) << 4) + (l & 15);
      int kl = (l >> 4) * 8;
      f16 v8[8];
      #pragma unroll
      for (int j = 0; j < 8; j++) v8[j] = (f16)lsA[(kl + j)*256 + n];
      *(uint4*)(wgB + ((size_t)kcg*1024 + o)*8) = *(const uint4*)v8;
    }
  } else {
    const int kcg = b - 128;           // 0..15, K=512
    #pragma unroll 8
    for (int i = 0; i < 32; i++){
      int kg = kcg*32 + i;
      lsA[i*256 + t] = (kg < 256) ? wz[(size_t)kg * UN + t]
                                  : uz[(size_t)(kg - 256) * UN + t];
      lsB[i*256 + t] = (kg < 256) ? wh[(size_t)kg * UN + t]
                                  : uh[(size_t)(kg - 256) * UN + t];
    }
    __syncthreads();
    #pragma unroll
    for (int i = 0; i < 4; i++){
      int o = i*256 + t;
      int l = o & 63;
      int n = ((o >> 6) << 4) + (l & 15);
      int kl = (l >> 4) * 8;
      f16 zh[8], zl[8], hh[8], hl[8];
      #pragma unroll
      for (int j = 0; j < 8; j++){
        float vz = lsA[(kl + j)*256 + n];
        float vh = lsB[(kl + j)*256 + n];
        f16 a = (f16)vz; zh[j] = a; zl[j] = (f16)(vz - (float)a);
        f16 c = (f16)vh; hh[j] = c; hl[j] = (f16)(vh - (float)c);
      }
      size_t off = ((size_t)kcg*1024 + o)*8;
      *(uint4*)(czB_h + off) = *(const uint4*)zh;
      *(uint4*)(czB_l + off) = *(const uint4*)zl;
      *(uint4*)(chB_h + off) = *(const uint4*)hh;
      *(uint4*)(chB_l + off) = *(const uint4*)hl;
    }
  }
}

// ---------------- K1: W2[node][unit] += (sum_g wa_g adj_g) @ w_gcn --------
// Block = 64m x 256n. LDS As[3][64][64] f32 staged via global_load_lds (48KB).
// Wave = 32m x 128n (2 m-frags x 8 n-frags). Grid (64 m-tiles, 16 k-splits).
__global__ __launch_bounds__(256) void k1_w2(
    const float* __restrict__ adj, const float* __restrict__ wa,
    const f16* __restrict__ wgB, float* __restrict__ W2)
{
  __shared__ float As[3*64*64];            // 48 KB
  const int t = threadIdx.x, lane = t & 63, wv = t >> 6;
  const int qm = lane & 15, quad = lane >> 4;
  const int mh = wv & 1, nh = wv >> 1;     // m-half (32 rows), n-half (128 cols)
  const int mbase = blockIdx.x * 64;
  const int kbase = blockIdx.y * 256;
  const float wa0 = wa[0], wa1 = wa[1], wa2 = wa[2];
  const size_t gs = (size_t)NN * NN;

  f32x4 acc[2][8];
  #pragma unroll
  for (int f = 0; f < 2; f++)
    #pragma unroll
    for (int i = 0; i < 8; i++) acc[f][i] = zero4();

  for (int it = 0; it < 4; it++){
    const int kt = kbase + it*64;
    // ---- stage 3 x 64 x 64 f32 tile: 48 wave-instrs, 12 per wave ----
    #pragma unroll
    for (int i = 0; i < 12; i++){
      const int ci = (wv*12 + i)*64;       // chunk base for this instr
      const int c  = ci + lane;            // this lane's chunk
      const int g  = c >> 10;              // graph
      const int r  = (c >> 4) & 63;        // row in tile
      const int kc = c & 15;               // 16B chunk in row
      stage16(&As[ci*4],
              adj + (size_t)g*gs + (size_t)(mbase + r)*NN + kt + kc*4);
    }
    __syncthreads();

    // ---- compute: 2 sub-steps of 32k ----
    #pragma unroll
    for (int kk = 0; kk < 2; kk++){
      f16x8 ah[2], al[2];
      #pragma unroll
      for (int f = 0; f < 2; f++){
        const int row = mh*32 + f*16 + qm;
        const int base = row*64 + kk*32 + quad*8;
        f32x4 a0 = *(const f32x4*)&As[base];
        f32x4 a1 = *(const f32x4*)&As[base + 4];
        f32x4 b0 = *(const f32x4*)&As[4096 + base];
        f32x4 b1 = *(const f32x4*)&As[4096 + base + 4];
        f32x4 c0 = *(const f32x4*)&As[8192 + base];
        f32x4 c1 = *(const f32x4*)&As[8192 + base + 4];
        #pragma unroll
        for (int j = 0; j < 4; j++){
          float v0 = wa0*a0[j] + wa1*b0[j] + wa2*c0[j];
          float v1 = wa0*a1[j] + wa1*b1[j] + wa2*c1[j];
          f16 h0 = (f16)v0, h1 = (f16)v1;
          ah[f][j] = h0;   al[f][j] = (f16)(v0 - (float)h0);
          ah[f][4+j] = h1; al[f][4+j] = (f16)(v1 - (float)h1);
        }
      }
      const int kcg = (kt + kk*32) >> 5;
      const f16* pb = wgB + ((size_t)kcg*1024 + nh*512 + lane)*8;
      f16x8 bfr[8];
      #pragma unroll
      for (int i = 0; i < 8; i++) bfr[i] = ld_f16x8(pb + i*512);
      #pragma unroll
      for (int tn = 0; tn < 8; tn++){
        #pragma unroll
        for (int f = 0; f < 2; f++){
          acc[f][tn] = __builtin_amdgcn_mfma_f32_16x16x32_f16(ah[f], bfr[tn], acc[f][tn], 0, 0, 0);
          acc[f][tn] = __builtin_amdgcn_mfma_f32_16x16x32_f16(al[f], bfr[tn], acc[f][tn], 0, 0, 0);
        }
      }
    }
    __syncthreads();
  }

  // epilogue: D[m=quad*4+r][n=(nh*8+tn)*16+qm]; 64B-coalesced f32 atomics
  #pragma unroll
  for (int f = 0; f < 2; f++)
    #pragma unroll
    for (int tn = 0; tn < 8; tn++)
      #pragma unroll
      for (int r = 0; r < 4; r++)
        atomicAdd(&W2[(size_t)(mbase + mh*32 + f*16 + quad*4 + r)*UN + (nh*8 + tn)*16 + qm],
                  acc[f][tn][r]);
}

// ---------------- Kcvt: W2 f32 [4096][256] -> W2B f16 frag-major ----------
__global__ __launch_bounds__(256) void k_cvt(
    const float* __restrict__ W2, f16* __restrict__ W2B)
{
  __shared__ float ls[32*256];
  const int t = threadIdx.x;
  const int kcg = blockIdx.x;            // 0..127
  #pragma unroll 8
  for (int i = 0; i < 32; i++)
    ls[i*256 + t] = W2[(size_t)(kcg*32 + i) * UN + t];
  __syncthreads();
  #pragma unroll
  for (int i = 0; i < 4; i++){
    int o = i*256 + t;
    int l = o & 63;
    int n = ((o >> 6) << 4) + (l & 15);
    int kl = (l >> 4) * 8;
    f16 v8[8];
    #pragma unroll
    for (int j = 0; j < 8; j++) v8[j] = (f16)ls[(kl + j)*256 + n];
    *(uint4*)(W2B + ((size_t)kcg*1024 + o)*8) = *(const uint4*)v8;
  }
}

// ---------------- K2: xg[m][n] += inputs @ W2 -----------------------------
// Grid (32 m-tiles of 16, 32 k-splits of 128). Parity-buffer prefetch.
__global__ __launch_bounds__(256) void k2_x(
    const float* __restrict__ inputs, const f16* __restrict__ W2B,
    float* __restrict__ xg)
{
  const int t = threadIdx.x, lane = t & 63, wv = t >> 6;
  const int qm = lane & 15, quad = lane >> 4;
  const int m0 = blockIdx.x * 16;
  const int kbase = blockIdx.y * 128;
  const float* pa = inputs + (size_t)(m0 + qm) * NN + kbase + quad * 8;

  f32x4 acc[4] = { zero4(), zero4(), zero4(), zero4() };

  f32x4 a0 = *(const f32x4*)pa;
  f32x4 a1 = *(const f32x4*)(pa + 4);
  f16x8 bf[4];
  {
    const f16* pb = W2B + (((size_t)(kbase >> 5)*16 + wv*4)*64 + lane)*8;
    #pragma unroll
    for (int i = 0; i < 4; i++) bf[i] = ld_f16x8(pb + i*512);
  }

  #pragma unroll
  for (int kc = 0; kc < 128; kc += 32){
    f32x4 na0, na1; f16x8 nb[4];
    if (kc < 96){
      na0 = *(const f32x4*)(pa + kc + 32);
      na1 = *(const f32x4*)(pa + kc + 36);
      const f16* pbn = W2B + (((size_t)((kbase + kc + 32) >> 5)*16 + wv*4)*64 + lane)*8;
      #pragma unroll
      for (int i = 0; i < 4; i++) nb[i] = ld_f16x8(pbn + i*512);
    }
    f16x8 ah, al;
    #pragma unroll
    for (int j = 0; j < 4; j++){
      f16 h0 = (f16)a0[j], h1 = (f16)a1[j];
      ah[j] = h0;   al[j] = (f16)(a0[j] - (float)h0);
      ah[4+j] = h1; al[4+j] = (f16)(a1[j] - (float)h1);
    }
    #pragma unroll
    for (int tn = 0; tn < 4; tn++){
      acc[tn] = __builtin_amdgcn_mfma_f32_16x16x32_f16(ah, bf[tn], acc[tn], 0, 0, 0);
      acc[tn] = __builtin_amdgcn_mfma_f32_16x16x32_f16(al, bf[tn], acc[tn], 0, 0, 0);
    }
    a0 = na0; a1 = na1;
    #pragma unroll
    for (int i = 0; i < 4; i++) bf[i] = nb[i];
  }
  #pragma unroll
  for (int tn = 0; tn < 4; tn++)
    #pragma unroll
    for (int r = 0; r < 4; r++)
      atomicAdd(&xg[(size_t)(m0 + quad*4 + r)*UN + (wv*4 + tn)*16 + qm],
                acc[tn][r]);
}

// ---------------- K3: gate logits via MFMA; relu+split fused --------------
// Grid (32 m-tiles of 16, 16 k-splits of 32). A read directly from xg/state.
__global__ __launch_bounds__(256) void k3_gates(
    const float* __restrict__ xg, const float* __restrict__ state,
    const f16* __restrict__ czB_h, const f16* __restrict__ czB_l,
    const f16* __restrict__ chB_h, const f16* __restrict__ chB_l,
    float* __restrict__ lz, float* __restrict__ lh)
{
  const int t = threadIdx.x, lane = t & 63, wv = t >> 6;
  const int qm = lane & 15, quad = lane >> 4;
  const int m0 = blockIdx.x * 16;
  const int kbase = blockIdx.y * 32;
  const bool rl = (kbase < 256);
  const float* asrc = rl ? (xg + (size_t)(m0 + qm)*UN + kbase + quad*8)
                         : (state + (size_t)(m0 + qm)*UN + (kbase - 256) + quad*8);

  f32x4 a0 = *(const f32x4*)asrc;
  f32x4 a1 = *(const f32x4*)(asrc + 4);
  f16x8 ah, al;
  #pragma unroll
  for (int j = 0; j < 4; j++){
    float v0 = rl ? fmaxf(a0[j], 0.f) : a0[j];
    float v1 = rl ? fmaxf(a1[j], 0.f) : a1[j];
    f16 h0 = (f16)v0, h1 = (f16)v1;
    ah[j] = h0;   al[j] = (f16)(v0 - (float)h0);
    ah[4+j] = h1; al[4+j] = (f16)(v1 - (float)h1);
  }

  f32x4 az[4] = { zero4(), zero4(), zero4(), zero4() };
  f32x4 ag[4] = { zero4(), zero4(), zero4(), zero4() };
  const int kcg = kbase >> 5;
  const size_t base = (((size_t)kcg*16 + wv*4)*64 + lane)*8;
  #pragma unroll
  for (int tn = 0; tn < 4; tn++){
    f16x8 bzh = ld_f16x8(czB_h + base + tn*512);
    f16x8 bzl = ld_f16x8(czB_l + base + tn*512);
    f16x8 bhh = ld_f16x8(chB_h + base + tn*512);
    f16x8 bhl = ld_f16x8(chB_l + base + tn*512);
    az[tn] = __builtin_amdgcn_mfma_f32_16x16x32_f16(ah, bzh, az[tn], 0, 0, 0);
    az[tn] = __builtin_amdgcn_mfma_f32_16x16x32_f16(al, bzh, az[tn], 0, 0, 0);
    az[tn] = __builtin_amdgcn_mfma_f32_16x16x32_f16(ah, bzl, az[tn], 0, 0, 0);
    ag[tn] = __builtin_amdgcn_mfma_f32_16x16x32_f16(ah, bhh, ag[tn], 0, 0, 0);
    ag[tn] = __builtin_amdgcn_mfma_f32_16x16x32_f16(al, bhh, ag[tn], 0, 0, 0);
    ag[tn] = __builtin_amdgcn_mfma_f32_16x16x32_f16(ah, bhl, ag[tn], 0, 0, 0);
  }
  #pragma unroll
  for (int tn = 0; tn < 4; tn++)
    #pragma unroll
    for (int r = 0; r < 4; r++){
      size_t o = (size_t)(m0 + quad*4 + r)*UN + (wv*4 + tn)*16 + qm;
      atomicAdd(&lz[o], az[tn][r]);
      atomicAdd(&lh[o], ag[tn][r]);
    }
}

// ---------------- K3b: elementwise gates + output -------------------------
__global__ __launch_bounds__(256) void k3b_out(
    const float* __restrict__ lz, const float* __restrict__ lh,
    const float* __restrict__ state,
    const float* __restrict__ bz, const float* __restrict__ bh,
    float* __restrict__ out)
{
  const size_t e = ((size_t)blockIdx.x * 256 + threadIdx.x) * 4;
  const int n = (int)(e & 255);
  f32x4 z4 = *(const f32x4*)(lz + e);
  f32x4 h4 = *(const f32x4*)(lh + e);
  f32x4 s4 = *(const f32x4*)(state + e);
  f32x4 bz4 = *(const f32x4*)(bz + n);
  f32x4 bh4 = *(const f32x4*)(bh + n);
  f32x4 o4;
  #pragma unroll
  for (int j = 0; j < 4; j++){
    float z = 1.f / (1.f + __expf(-(z4[j] + bz4[j])));
    float ex = __expf(2.f * (h4[j] + bh4[j]));
    float hh = 1.f - 2.f / (ex + 1.f);
    o4[j] = (1.f - z) * s4[j] + z * hh;
  }
  *(f32x4*)(out + e) = o4;
}

// ---------------- launch --------------------------------------------------
extern "C" void kernel_launch(void* const* d_in, const int* in_sizes, int n_in,
                              void* d_out, int out_size, void* d_ws, size_t ws_size,
                              hipStream_t stream)
{
  const float* inputs = (const float*)d_in[0];
  const float* state  = (const float*)d_in[1];
  const float* adj    = (const float*)d_in[2];
  const float* wa     = (const float*)d_in[3];
  const float* wg     = (const float*)d_in[4];
  const float* wz     = (const float*)d_in[5];
  const float* uz     = (const float*)d_in[6];
  const float* bz     = (const float*)d_in[7];
  const float* wh     = (const float*)d_in[8];
  const float* uh     = (const float*)d_in[9];
  const float* bh     = (const float*)d_in[10];
  float* out = (float*)d_out;

  char* ws = (char*)d_ws;
  float* W2    = (float*)(ws);                          // 4 MB [4096][256] f32
  float* xg    = (float*)(ws + (4u<<20));               // 512 KB [512][256]
  float* lz    = (float*)(ws + (4u<<20) + (512u<<10));  // 512 KB
  float* lh    = (float*)(ws + (5u<<20));               // 512 KB
  f16* wgB     = (f16*)(ws + (5u<<20) + (512u<<10));    // 2 MB frag-major
  f16* W2B     = (f16*)(ws + (7u<<20) + (512u<<10));    // 2 MB frag-major
  f16* czB_h   = (f16*)(ws + (9u<<20) + (512u<<10));    // 256 KB
  f16* czB_l   = (f16*)(ws + (9u<<20) + (768u<<10));    // 256 KB
  f16* chB_h   = (f16*)(ws + (10u<<20));                // 256 KB
  f16* chB_l   = (f16*)(ws + (10u<<20) + (256u<<10));   // 256 KB

  // zero W2 + xg + lz + lh (contiguous 5.5 MB)
  hipMemsetAsync(ws, 0, (5u<<20) + (512u<<10), stream);
  k0_prep<<<144, 256, 0, stream>>>(wg, wz, uz, wh, uh,
                                   wgB, czB_h, czB_l, chB_h, chB_l);
  k1_w2<<<dim3(64, 16), 256, 0, stream>>>(adj, wa, wgB, W2);
  k_cvt<<<128, 256, 0, stream>>>(W2, W2B);
  k2_x<<<dim3(32, 32), 256, 0, stream>>>(inputs, W2B, xg);
  k3_gates<<<dim3(32, 16), 256, 0, stream>>>(xg, state, czB_h, czB_l,
                                             chB_h, chB_l, lz, lh);
  k3b_out<<<128, 256, 0, stream>>>(lz, lh, state, bz, bh, out);
}